// Round 16
// baseline (89.321 us; speedup 1.0000x reference)
//
#include <hip/hip_runtime.h>
#include <hip/hip_bf16.h>

// y[b,i,j] = s[b,i] + s[b,j] - 2 * sum_k U[b,i,k]*U[b,j,k],  U = bf16(g^t * V)
//   (w*Vi*Vj = (g^t Vi)(g^t Vj), w = max(G,0)^(2t))  s[b,i] = sum_k U[b,i,k]^2
// bs=4, r=4096, d=64. Output 268 MB fp32 -> write-bandwidth bound; dist is
// at its mixed-stream plateau (~60us) across 10 structural variants.
// R15 -> R16: FUSE prep into dist to remove the remaining fixed overhead
// (prep run ~3us + dispatch gap ~2us). A 1-block micro-kernel computes
// sw[b][k]=max(G,0)^t (256 floats); dist loads V fp32 (L2-resident),
// converts bf16(sw*v) in-register (same rounding as prep did), and builds
// s in-register via shfl_xor(16/32) butterfly over the fragment k-slices.
// Memory schedule/epilogue byte-identical to R15 (best: 64.5us).

typedef __attribute__((ext_vector_type(8))) short bf16x8;   // 8 bf16 = 4 VGPRs
typedef __attribute__((ext_vector_type(4))) float f32x4;

constexpr int BS = 4, R = 4096, D = 64;
constexpr int LS = 260;   // LDS row stride (floats): 16B-aligned rows, 2-way max conflict (free)

__device__ __forceinline__ void barrier_lds_only() {
    // order LDS ops, but let global stores stay in flight
    asm volatile("s_waitcnt lgkmcnt(0)" ::: "memory");
    __builtin_amdgcn_sched_barrier(0);
    __builtin_amdgcn_s_barrier();
    __builtin_amdgcn_sched_barrier(0);
}

// ------------------------------------------------------------- sw micro -----
// 1 block, 256 threads: sw[b*D+k] = max(G,0)^t. Guarded fast powf.
__global__ __launch_bounds__(256) void sw_kernel(
    const float* __restrict__ G, const float* __restrict__ wt,
    float* __restrict__ sw)
{
    int i = threadIdx.x;                 // BS*D == 256
    float t = wt[0];
    float g = fmaxf(G[i], 0.0f);
    float r;
    if (g > 0.0f) r = __powf(g, t);      // fast exp2/log2 path; rel err ~2^-21
    else          r = (t == 0.0f) ? 1.0f : 0.0f;   // 0^0=1 matches jnp
    sw[i] = r;
}

// ---------------------------------------------------------------- dist ------
// Block: 512 threads = 8 waves, arranged 2 (i) x 4 (j); wave tile 64x64.
// Block tile 128 (i) x 256 (j). Grid: (R/256 j [FAST], R/128 i, BS).
// MFMA 16x16x32 bf16 layouts (HW-verified, learn_hip m89/m91/m97):
//   A: lane holds A[row=l&15][k=(l>>4)*8 + 0..7]   (contiguous 16B)
//   B: lane holds B[k=(l>>4)*8 + 0..7][col=l&15] == U[j0+(l&15)][k...] for B=U^T
//   C/D: col = l&15, row = (l>>4)*4 + reg
// U fragments built in-register from V fp32 + sw; s built via shfl_xor
// butterfly (lanes {x, x+16, x+32, x+48} hold the 4 k-octets of one row).
// Epilogue: two 64-row chunks: y -> LDS[64][260] -> full-row 1KB stores.
__global__ __launch_bounds__(512, 4) void dist_kernel(
    const float* __restrict__ V, const float* __restrict__ sw,
    float* __restrict__ out)
{
    __shared__ float lds[64 * LS];   // 66.5 KB -> 2 blocks/CU

    int lane = threadIdx.x & 63;
    int wave = threadIdx.x >> 6;     // 0..7
    int wr   = wave >> 2;            // 0..1  (i half)
    int wc   = wave & 3;             // 0..3  (j quarter)

    int b  = blockIdx.z;
    int jb = blockIdx.x * 256;       // FAST axis: j -> contiguous write window
    int i0 = blockIdx.y * 128;

    int lrow = lane & 15;
    int kgrp = lane >> 4;            // 0..3

    const float* Vb  = V + (size_t)b * R * D;
    const float* swb = sw + b * D;

    // sw for this lane's two k-octets (k = ks*32 + kgrp*8 + 0..7)
    f32x4 sw0a = *(const f32x4*)(swb +      kgrp * 8);
    f32x4 sw0b = *(const f32x4*)(swb +      kgrp * 8 + 4);
    f32x4 sw1a = *(const f32x4*)(swb + 32 + kgrp * 8);
    f32x4 sw1b = *(const f32x4*)(swb + 32 + kgrp * 8 + 4);

    // convert one 8-float octet: u = bf16(sw*v); accumulate p += u^2 (rounded)
    auto cvt8 = [](const float* vp, const f32x4& wa, const f32x4& wb, float& p) {
        f32x4 v0 = *(const f32x4*)vp;
        f32x4 v1 = *(const f32x4*)(vp + 4);
        bf16x8 r;
        #pragma unroll
        for (int i = 0; i < 4; ++i) {
            __hip_bfloat16 h = __float2bfloat16(wa[i] * v0[i]);
            unsigned short bits; __builtin_memcpy(&bits, &h, 2);
            r[i] = (short)bits;
            float uf = __bfloat162float(h);
            p = fmaf(uf, uf, p);
        }
        #pragma unroll
        for (int i = 0; i < 4; ++i) {
            __hip_bfloat16 h = __float2bfloat16(wb[i] * v1[i]);
            unsigned short bits; __builtin_memcpy(&bits, &h, 2);
            r[4 + i] = (short)bits;
            float uf = __bfloat162float(h);
            p = fmaf(uf, uf, p);
        }
        return r;
    };

    // A fragments + si: 4 row-blocks x 2 K-steps
    bf16x8 a[4][2];
    float si_lane = 0.0f;            // lane l ends holding s of local A-row l
    #pragma unroll
    for (int rb = 0; rb < 4; ++rb) {
        const float* vp = Vb + (size_t)(i0 + wr * 64 + rb * 16 + lrow) * D + kgrp * 8;
        float p = 0.0f;
        a[rb][0] = cvt8(vp,      sw0a, sw0b, p);
        a[rb][1] = cvt8(vp + 32, sw1a, sw1b, p);
        p += __shfl_xor(p, 16);
        p += __shfl_xor(p, 32);      // all 4 k-octet lanes now hold row sum
        if (kgrp == rb) si_lane = p; // lane l = row (l>>4)*16+(l&15): pick rb==l>>4
    }

    f32x4 acc[4][4];
    #pragma unroll
    for (int rb = 0; rb < 4; ++rb)
        #pragma unroll
        for (int jt = 0; jt < 4; ++jt)
            acc[rb][jt] = f32x4{0.f, 0.f, 0.f, 0.f};

    float sB[4];
    #pragma unroll
    for (int jt = 0; jt < 4; ++jt) {
        const float* vp = Vb + (size_t)(jb + wc * 64 + jt * 16 + lrow) * D + kgrp * 8;
        float p = 0.0f;
        bf16x8 b0 = cvt8(vp,      sw0a, sw0b, p);
        bf16x8 b1 = cvt8(vp + 32, sw1a, sw1b, p);
        p += __shfl_xor(p, 16);
        p += __shfl_xor(p, 32);
        sB[jt] = p;                  // s of B-row jt*16 + lrow (what epilogue needs)
        #pragma unroll
        for (int rb = 0; rb < 4; ++rb) {
            acc[rb][jt] = __builtin_amdgcn_mfma_f32_16x16x32_bf16(a[rb][0], b0, acc[rb][jt], 0, 0, 0);
            acc[rb][jt] = __builtin_amdgcn_mfma_f32_16x16x32_bf16(a[rb][1], b1, acc[rb][jt], 0, 0, 0);
        }
    }

    float* outb = out + ((size_t)b * R + i0) * R + jb;

    #pragma unroll
    for (int c = 0; c < 2; ++c) {
        // chunk c covers block rows c*64 .. c*64+63 (i.e. waves with wr==c)
        if (wr == c) {
            #pragma unroll
            for (int rb = 0; rb < 4; ++rb) {
                #pragma unroll
                for (int rg = 0; rg < 4; ++rg) {
                    int rl = rb * 16 + kgrp * 4 + rg;          // 0..63 local row
                    float si = __shfl(si_lane, rl);
                    #pragma unroll
                    for (int jt = 0; jt < 4; ++jt) {
                        float y  = si + sB[jt] - 2.0f * acc[rb][jt][rg];
                        lds[rl * LS + wc * 64 + jt * 16 + lrow] = y;
                    }
                }
            }
        }
        barrier_lds_only();   // ds_writes visible; in-flight global stores NOT drained

        // all 8 waves store chunk c: wave w -> rows w*8..w*8+7 of the chunk.
        // Each instruction: 64 lanes x 16B = one contiguous 1KB segment.
        #pragma unroll
        for (int r = 0; r < 8; ++r) {
            int rl = wave * 8 + r;
            f32x4 v = *(const f32x4*)&lds[rl * LS + lane * 4];
            *(f32x4*)(outb + (size_t)(c * 64 + rl) * R + lane * 4) = v;
        }
        if (c == 0) barrier_lds_only();   // ds_reads done -> chunk-1 may overwrite LDS
    }
}

// --------------------------------------------------------------------------
extern "C" void kernel_launch(void* const* d_in, const int* in_sizes, int n_in,
                              void* d_out, int out_size, void* d_ws, size_t ws_size,
                              hipStream_t stream) {
    const float* G  = (const float*)d_in[0];
    const float* V  = (const float*)d_in[1];
    const float* wt = (const float*)d_in[2];
    float* out = (float*)d_out;

    float* swbuf = (float*)d_ws;     // 256 floats = 1 KB

    sw_kernel<<<1, 256, 0, stream>>>(G, wt, swbuf);

    dim3 grid(R / 256, R / 128, BS);   // j fastest -> contiguous write window
    dist_kernel<<<grid, 512, 0, stream>>>(V, swbuf, out);
}

// Round 17
// 65.084 us; speedup vs baseline: 1.3724x; 1.3724x over previous
//
#include <hip/hip_runtime.h>
#include <hip/hip_bf16.h>

// y[b,i,j] = s[b,i] + s[b,j] - 2 * sum_k U[b,i,k]*U[b,j,k],  U = bf16(g^t * V)
//   (w*Vi*Vj = (g^t Vi)(g^t Vj), w = max(G,0)^(2t))  s[b,i] = sum_k U[b,i,k]^2
// bs=4, r=4096, d=64. Output 268 MB fp32 -> write-bandwidth bound.
// R16 -> R17: restore R15 (best measured: 64.5 us). R16's fusion regressed
// (per-block re-conversion of B panels ~16x + fp32 read amplification).
// Final structure: prep (bf16 U + fp32 s, converted exactly once) + dist
// (128x256 block tile, 8 waves of 64x64, 16x16x32 MFMA, LDS-staged
// full-line 1KB dwordx4 stores, lgkm-only barriers, j-fastest grid).

typedef __attribute__((ext_vector_type(8))) short bf16x8;   // 8 bf16 = 4 VGPRs
typedef __attribute__((ext_vector_type(4))) float f32x4;

constexpr int BS = 4, R = 4096, D = 64;
constexpr int LS = 260;   // LDS row stride (floats): 16B-aligned rows, 2-way max conflict (free)

__device__ __forceinline__ void barrier_lds_only() {
    // order LDS ops, but let global stores stay in flight
    asm volatile("s_waitcnt lgkmcnt(0)" ::: "memory");
    __builtin_amdgcn_sched_barrier(0);
    __builtin_amdgcn_s_barrier();
    __builtin_amdgcn_sched_barrier(0);
}

// ---------------------------------------------------------------- prep ------
// One wave per row (64 lanes == d). Emits U = bf16(g^t * V), fp32 s = sum U^2.
__global__ __launch_bounds__(256) void prep_kernel(
    const float* __restrict__ G, const float* __restrict__ V,
    const float* __restrict__ wt,
    __hip_bfloat16* __restrict__ u_bf, float* __restrict__ s)
{
    int row  = blockIdx.x * 4 + (threadIdx.x >> 6);   // global row in [0, BS*R)
    int lane = threadIdx.x & 63;                       // k index (d == 64)
    if (row >= BS * R) return;
    int b = row / R;

    float t  = wt[0];
    float g  = fmaxf(G[b * D + lane], 0.0f);
    float sw = powf(g, t);                             // g^t; 0^0==1 matches jnp
    float u  = sw * V[(size_t)row * D + lane];

    __hip_bfloat16 ub = __float2bfloat16(u);
    u_bf[(size_t)row * D + lane] = ub;

    // s from the same bf16-rounded values -> diagonal cancels vs MFMA cross
    float uf   = __bfloat162float(ub);
    float prod = uf * uf;
    #pragma unroll
    for (int off = 32; off; off >>= 1) prod += __shfl_down(prod, off);
    if (lane == 0) s[row] = prod;
}

// ---------------------------------------------------------------- dist ------
// Block: 512 threads = 8 waves, arranged 2 (i) x 4 (j); wave tile 64x64.
// Block tile 128 (i) x 256 (j). Grid: (R/256 j [FAST], R/128 i, BS).
// MFMA 16x16x32 bf16 layouts (HW-verified, learn_hip m89/m91/m97):
//   A: lane holds A[row=l&15][k=(l>>4)*8 + 0..7]   (contiguous 16B)
//   B: lane holds B[k=(l>>4)*8 + 0..7][col=l&15] == U[j0+(l&15)][k...] for B=U^T
//   C/D: col = l&15, row = (l>>4)*4 + reg
// Epilogue: two 64-row chunks: y -> LDS[64][260] -> full-row 1KB stores.
__global__ __launch_bounds__(512) void dist_kernel(
    const short* __restrict__ U, const float* __restrict__ s,
    float* __restrict__ out)
{
    __shared__ float lds[64 * LS];   // 66.5 KB -> 2 blocks/CU

    int lane = threadIdx.x & 63;
    int wave = threadIdx.x >> 6;     // 0..7
    int wr   = wave >> 2;            // 0..1  (i half)
    int wc   = wave & 3;             // 0..3  (j quarter)

    int b  = blockIdx.z;
    int jb = blockIdx.x * 256;       // FAST axis: j -> contiguous write window
    int i0 = blockIdx.y * 128;

    const short* Ap = U + ((size_t)b * R + i0 + wr * 64) * D;   // 64 rows
    const short* Bp = U + ((size_t)b * R + jb + wc * 64) * D;   // 64 rows
    const float* sb = s + (size_t)b * R;

    int lrow = lane & 15;
    int kgrp = lane >> 4;            // 0..3

    // A fragments: 4 row-blocks x 2 K-steps
    bf16x8 a[4][2];
    #pragma unroll
    for (int rb = 0; rb < 4; ++rb)
        #pragma unroll
        for (int ks = 0; ks < 2; ++ks)
            a[rb][ks] = *(const bf16x8*)(Ap + (rb * 16 + lrow) * D + ks * 32 + kgrp * 8);

    f32x4 acc[4][4];
    #pragma unroll
    for (int rb = 0; rb < 4; ++rb)
        #pragma unroll
        for (int jt = 0; jt < 4; ++jt)
            acc[rb][jt] = f32x4{0.f, 0.f, 0.f, 0.f};

    #pragma unroll
    for (int jt = 0; jt < 4; ++jt) {
        const short* Bt = Bp + jt * 16 * D;
        bf16x8 b0 = *(const bf16x8*)(Bt + lrow * D +      kgrp * 8);
        bf16x8 b1 = *(const bf16x8*)(Bt + lrow * D + 32 + kgrp * 8);
        #pragma unroll
        for (int rb = 0; rb < 4; ++rb) {
            acc[rb][jt] = __builtin_amdgcn_mfma_f32_16x16x32_bf16(a[rb][0], b0, acc[rb][jt], 0, 0, 0);
            acc[rb][jt] = __builtin_amdgcn_mfma_f32_16x16x32_bf16(a[rb][1], b1, acc[rb][jt], 0, 0, 0);
        }
    }

    // per-lane row sums for this wave's 64 rows
    float si_lane = sb[i0 + wr * 64 + lane];

    float* outb = out + ((size_t)b * R + i0) * R + jb;

    #pragma unroll
    for (int c = 0; c < 2; ++c) {
        // chunk c covers block rows c*64 .. c*64+63 (i.e. waves with wr==c)
        if (wr == c) {
            #pragma unroll
            for (int rb = 0; rb < 4; ++rb) {
                #pragma unroll
                for (int rg = 0; rg < 4; ++rg) {
                    int rl = rb * 16 + kgrp * 4 + rg;          // 0..63 local row
                    float si = __shfl(si_lane, rl);
                    #pragma unroll
                    for (int jt = 0; jt < 4; ++jt) {
                        float sj = sb[jb + wc * 64 + jt * 16 + lrow];
                        float y  = si + sj - 2.0f * acc[rb][jt][rg];
                        lds[rl * LS + wc * 64 + jt * 16 + lrow] = y;
                    }
                }
            }
        }
        barrier_lds_only();   // ds_writes visible; in-flight global stores NOT drained

        // all 8 waves store chunk c: wave w -> rows w*8..w*8+7 of the chunk.
        // Each instruction: 64 lanes x 16B = one contiguous 1KB segment.
        #pragma unroll
        for (int r = 0; r < 8; ++r) {
            int rl = wave * 8 + r;
            f32x4 v = *(const f32x4*)&lds[rl * LS + lane * 4];
            *(f32x4*)(outb + (size_t)(c * 64 + rl) * R + lane * 4) = v;
        }
        if (c == 0) barrier_lds_only();   // ds_reads done -> chunk-1 may overwrite LDS
    }
}

// --------------------------------------------------------------------------
extern "C" void kernel_launch(void* const* d_in, const int* in_sizes, int n_in,
                              void* d_out, int out_size, void* d_ws, size_t ws_size,
                              hipStream_t stream) {
    const float* G  = (const float*)d_in[0];
    const float* V  = (const float*)d_in[1];
    const float* wt = (const float*)d_in[2];
    float* out = (float*)d_out;

    char* ws = (char*)d_ws;
    __hip_bfloat16* u_bf = (__hip_bfloat16*)ws;                             // 2 MB
    float*          s    = (float*)        (ws + (size_t)BS * R * D * 2);   // 64 KB

    prep_kernel<<<BS * R / 4, 256, 0, stream>>>(G, V, wt, u_bf, s);

    dim3 grid(R / 256, R / 128, BS);   // j fastest -> contiguous write window
    dist_kernel<<<grid, 512, 0, stream>>>((const short*)u_bf, s, out);
}